// Round 1
// baseline (1076.496 us; speedup 1.0000x reference)
//
#include <hip/hip_runtime.h>

typedef __attribute__((ext_vector_type(4))) float f32x4;
typedef __attribute__((ext_vector_type(8))) __bf16 bf16x8;
typedef unsigned short ushort_t;
typedef unsigned int uint_t;

// ---------- bf16 helpers (manual, RNE) ----------
__device__ __forceinline__ float bf2f(ushort_t u) {
  union { uint_t i; float f; } v; v.i = ((uint_t)u) << 16; return v.f;
}
__device__ __forceinline__ ushort_t f2bf(float f) {
  union { float f; uint_t i; } v; v.f = f;
  uint_t x = v.i;
  return (ushort_t)((x + 0x7fffu + ((x >> 16) & 1u)) >> 16);
}

// ---------- async global->LDS, 16B ----------
__device__ __forceinline__ void gload_lds16(const void* g, void* l) {
  __builtin_amdgcn_global_load_lds(
      (const __attribute__((address_space(1))) void*)g,
      (__attribute__((address_space(3))) void*)l, 16, 0, 0);
}

// ---------- 1) fp32 -> bf16 cast (8 elems/thread) ----------
__global__ __launch_bounds__(256) void cast_bf16_kernel(
    const float* __restrict__ in, ushort_t* __restrict__ out, int n8) {
  int i = blockIdx.x * 256 + threadIdx.x;
  if (i >= n8) return;
  float4 a = ((const float4*)in)[i * 2];
  float4 b = ((const float4*)in)[i * 2 + 1];
  ushort4 o0 = make_ushort4(f2bf(a.x), f2bf(a.y), f2bf(a.z), f2bf(a.w));
  ushort4 o1 = make_ushort4(f2bf(b.x), f2bf(b.y), f2bf(b.z), f2bf(b.w));
  ((ushort4*)out)[i * 2] = o0;
  ((ushort4*)out)[i * 2 + 1] = o1;
}

// ---------- 2) transpose + cast: in (R,C) fp32 -> out (C,R) bf16 ----------
__global__ __launch_bounds__(256) void transpose_cast_kernel(
    const float* __restrict__ in, ushort_t* __restrict__ out, int R, int C) {
  __shared__ float tile[32][33];
  int tx = threadIdx.x, ty = threadIdx.y;
  int c0 = blockIdx.x * 32, r0 = blockIdx.y * 32;
#pragma unroll
  for (int i = 0; i < 4; ++i)
    tile[ty + i * 8][tx] = in[(size_t)(r0 + ty + i * 8) * C + c0 + tx];
  __syncthreads();
#pragma unroll
  for (int i = 0; i < 4; ++i)
    out[(size_t)(c0 + ty + i * 8) * R + r0 + tx] = f2bf(tile[tx][ty + i * 8]);
}

// ---------- 3) GEMM: C(M,N) = A(M,K)bf16 * BT(N,K)bf16 ----------
// 128x128 tile, BK=32, 4 waves (2x2), each wave 64x64 via 4x4 16x16x32 MFMAs.
template <int OUT_BF16>
__global__ __launch_bounds__(256, 2) void gemm_bt_kernel(
    const ushort_t* __restrict__ A, const ushort_t* __restrict__ BT,
    void* __restrict__ Cout, int M, int N, int K) {
  __shared__ ushort_t As[128 * 32];
  __shared__ ushort_t Bs[128 * 32];
  const int tid = threadIdx.x;
  const int lane = tid & 63;
  const int wid = tid >> 6;
  const int wr = wid >> 1, wc = wid & 1;
  const int qr = lane & 15, kg = lane >> 4;
  const size_t arow = (size_t)blockIdx.y * 128;
  const size_t brow = (size_t)blockIdx.x * 128;

  f32x4 acc[4][4] = {};

  for (int k0 = 0; k0 < K; k0 += 32) {
    __syncthreads();
#pragma unroll
    for (int t = 0; t < 2; ++t) {
      int c = (t * 4 + wid) * 64 + lane;
      int r = c >> 2, kc = (c & 3) * 8;
      gload_lds16(A + (arow + r) * K + k0 + kc, &As[(t * 4 + wid) * 512]);
      gload_lds16(BT + (brow + r) * K + k0 + kc, &Bs[(t * 4 + wid) * 512]);
    }
    __syncthreads();
    bf16x8 af[4], bfr[4];
#pragma unroll
    for (int m = 0; m < 4; ++m)
      af[m] = *(const bf16x8*)&As[(wr * 64 + m * 16 + qr) * 32 + kg * 8];
#pragma unroll
    for (int n = 0; n < 4; ++n)
      bfr[n] = *(const bf16x8*)&Bs[(wc * 64 + n * 16 + qr) * 32 + kg * 8];
#pragma unroll
    for (int m = 0; m < 4; ++m)
#pragma unroll
      for (int n = 0; n < 4; ++n)
        acc[m][n] = __builtin_amdgcn_mfma_f32_16x16x32_bf16(af[m], bfr[n], acc[m][n], 0, 0, 0);
  }

#pragma unroll
  for (int m = 0; m < 4; ++m)
#pragma unroll
    for (int n = 0; n < 4; ++n)
#pragma unroll
      for (int j = 0; j < 4; ++j) {
        size_t row = arow + wr * 64 + m * 16 + kg * 4 + j;
        size_t col = brow + wc * 64 + n * 16 + qr;
        float v = acc[m][n][j];
        if (OUT_BF16) ((ushort_t*)Cout)[row * N + col] = f2bf(v);
        else ((float*)Cout)[row * N + col] = v;
      }
}

// ---------- 4) fused Gemma-RMSNorm + RoPE on q/k rows of qkv, in place ----------
// one wave per (token, head-slot); slots 0..15 = q heads, 16..17 = k heads.
__global__ __launch_bounds__(256) void normrope_kernel(
    ushort_t* __restrict__ qkv, const int* __restrict__ positions,
    const float* __restrict__ qw, const float* __restrict__ kw) {
  const int wv = blockIdx.x * 4 + (threadIdx.x >> 6);
  const int lane = threadIdx.x & 63;
  const int t = wv / 18;
  const int idx = wv % 18;
  size_t base;
  const float* w;
  if (idx < 16) { base = (size_t)t * 9216 + idx * 512; w = qw; }
  else { base = (size_t)t * 9216 + 8192 + (size_t)(idx - 16) * 256; w = kw; }

  ushort4 raw = *(const ushort4*)(qkv + base + lane * 4);
  float x0 = bf2f(raw.x), x1 = bf2f(raw.y), x2 = bf2f(raw.z), x3 = bf2f(raw.w);
  float ss = x0 * x0 + x1 * x1 + x2 * x2 + x3 * x3;
#pragma unroll
  for (int off = 1; off < 64; off <<= 1) ss += __shfl_xor(ss, off);
  float inv = rsqrtf(ss * (1.0f / 256.0f) + 1e-6f);
  const int d0 = lane * 4;
  float xn[4] = { x0 * inv * (1.f + w[d0]), x1 * inv * (1.f + w[d0 + 1]),
                  x2 * inv * (1.f + w[d0 + 2]), x3 * inv * (1.f + w[d0 + 3]) };
  float pn[4];
#pragma unroll
  for (int j = 0; j < 4; ++j) pn[j] = __shfl_xor(xn[j], 8);
  if (lane < 16) {
    const float pos = (float)positions[t];
#pragma unroll
    for (int j = 0; j < 4; ++j) {
      int d = d0 + j;
      int i = d & 31;
      float invf = __expf(-(float)i * 0.28782313662425574f);  // 10000^(-i/32)
      float fr = pos * invf;
      float s, c;
      sincosf(fr, &s, &c);
      xn[j] = (d < 32) ? (xn[j] * c - pn[j] * s) : (xn[j] * c + pn[j] * s);
    }
  }
  ushort4 o = make_ushort4(f2bf(xn[0]), f2bf(xn[1]), f2bf(xn[2]), f2bf(xn[3]));
  *(ushort4*)(qkv + base + lane * 4) = o;
}

// ---------- 5) causal flash attention + sigmoid gate ----------
// block = (qt, h): 64 q rows, 4 waves x 16 rows. KV tiles of 32.
__global__ __launch_bounds__(256, 2) void attn_kernel(
    const ushort_t* __restrict__ qkv, ushort_t* __restrict__ A2) {
  const int qt = blockIdx.x;
  const int h = blockIdx.y;
  const int kvh = h >> 3;
  const int tid = threadIdx.x;
  const int lane = tid & 63;
  const int wid = tid >> 6;
  const int qr = lane & 15, kg = lane >> 4;

  __shared__ ushort_t Ks[32 * 256];      // [kv][d], 16B-chunk XOR swizzled
  __shared__ ushort_t Vt[256 * 32];      // [d][kv], chunk XOR swizzled
  __shared__ ushort_t Ps[4][16 * 32];    // per-wave P tile [q16][kv32]

  const int q0 = qt * 64;
  const int myq0 = q0 + wid * 16;

  bf16x8 qf[8];
#pragma unroll
  for (int kd = 0; kd < 8; ++kd)
    qf[kd] = *(const bf16x8*)(qkv + (size_t)(myq0 + qr) * 9216 + h * 512 + kd * 32 + kg * 8);

  f32x4 o[16] = {};
  float mrun[4], lrun[4];
#pragma unroll
  for (int j = 0; j < 4; ++j) { mrun[j] = -1e30f; lrun[j] = 0.f; }

  const int ntiles = qt * 2 + 2;
  for (int kt = 0; kt < ntiles; ++kt) {
    const int kv0 = kt * 32;
    __syncthreads();
    // stage K: 1024 chunks of 16B; LDS linear, global source pre-swizzled
#pragma unroll
    for (int t = 0; t < 4; ++t) {
      int c = (t * 4 + wid) * 64 + lane;
      int r = c >> 5, dc = c & 31;
      int dcs = dc ^ (r & 7);
      gload_lds16(qkv + (size_t)(kv0 + r) * 9216 + 8192 + kvh * 256 + dcs * 8,
                  &Ks[(t * 4 + wid) * 512]);
    }
    // stage V^T via register transpose (packed b32 writes), swizzled
#pragma unroll
    for (int t = 0; t < 2; ++t) {
      int p = tid + 256 * t;
      int kvp = (p & 15) * 2, dc = p >> 4;
      const ushort_t* g0 = qkv + (size_t)(kv0 + kvp) * 9216 + 8704 + kvh * 256 + dc * 8;
      ushort4 a0 = *(const ushort4*)g0;
      ushort4 a1 = *(const ushort4*)(g0 + 4);
      ushort4 b0 = *(const ushort4*)(g0 + 9216);
      ushort4 b1 = *(const ushort4*)(g0 + 9216 + 4);
      uint_t vals[8];
      vals[0] = a0.x | ((uint_t)b0.x << 16); vals[1] = a0.y | ((uint_t)b0.y << 16);
      vals[2] = a0.z | ((uint_t)b0.z << 16); vals[3] = a0.w | ((uint_t)b0.w << 16);
      vals[4] = a1.x | ((uint_t)b1.x << 16); vals[5] = a1.y | ((uint_t)b1.y << 16);
      vals[6] = a1.z | ((uint_t)b1.z << 16); vals[7] = a1.w | ((uint_t)b1.w << 16);
#pragma unroll
      for (int j = 0; j < 8; ++j) {
        int d = dc * 8 + j;
        int boff = d * 64 + (((kvp >> 3) ^ (d & 3)) * 16) + ((kvp * 2) & 15);
        *(uint_t*)((char*)Vt + boff) = vals[j];
      }
    }
    __syncthreads();

    const bool active = (kv0 <= myq0 + 15);  // wave-uniform causal skip
    if (active) {
      f32x4 s0 = {0.f, 0.f, 0.f, 0.f}, s1 = {0.f, 0.f, 0.f, 0.f};
#pragma unroll
      for (int kd = 0; kd < 8; ++kd) {
        int kvr0 = qr;
        int off0 = kvr0 * 512 + ((kd * 64 + kg * 16) ^ ((kvr0 & 7) << 4));
        bf16x8 kf0 = *(const bf16x8*)((const char*)Ks + off0);
        s0 = __builtin_amdgcn_mfma_f32_16x16x32_bf16(qf[kd], kf0, s0, 0, 0, 0);
        int kvr1 = 16 + qr;
        int off1 = kvr1 * 512 + ((kd * 64 + kg * 16) ^ ((kvr1 & 7) << 4));
        bf16x8 kf1 = *(const bf16x8*)((const char*)Ks + off1);
        s1 = __builtin_amdgcn_mfma_f32_16x16x32_bf16(qf[kd], kf1, s1, 0, 0, 0);
      }
      // online softmax (per lane: 4 q-rows = kg*4+j; kv cols = n*16+qr)
#pragma unroll
      for (int j = 0; j < 4; ++j) {
        int qg = myq0 + kg * 4 + j;
        float v0 = s0[j] * 0.0625f, v1 = s1[j] * 0.0625f;
        if (kv0 + qr > qg) v0 = -1e30f;
        if (kv0 + 16 + qr > qg) v1 = -1e30f;
        float tm = fmaxf(v0, v1);
#pragma unroll
        for (int off = 1; off < 16; off <<= 1) tm = fmaxf(tm, __shfl_xor(tm, off));
        float mnew = fmaxf(mrun[j], tm);
        float corr = __expf(mrun[j] - mnew);
        mrun[j] = mnew;
        float p0 = __expf(v0 - mnew), p1 = __expf(v1 - mnew);
        float ps = p0 + p1;
#pragma unroll
        for (int off = 1; off < 16; off <<= 1) ps += __shfl_xor(ps, off);
        lrun[j] = lrun[j] * corr + ps;
#pragma unroll
        for (int n = 0; n < 16; ++n) o[n][j] *= corr;
        Ps[wid][(kg * 4 + j) * 32 + qr] = f2bf(p0);
        Ps[wid][(kg * 4 + j) * 32 + 16 + qr] = f2bf(p1);
      }
      asm volatile("" ::: "memory");  // order P writes before P read (same wave)
      bf16x8 pf = *(const bf16x8*)&Ps[wid][qr * 32 + kg * 8];
#pragma unroll
      for (int n = 0; n < 16; ++n) {
        int dcol = n * 16 + qr;
        int boff = dcol * 64 + ((kg ^ (dcol & 3)) * 16);
        bf16x8 vf = *(const bf16x8*)((const char*)Vt + boff);
        o[n] = __builtin_amdgcn_mfma_f32_16x16x32_bf16(pf, vf, o[n], 0, 0, 0);
      }
    }
  }

  // epilogue: 1/l, sigmoid gate, bf16 store
#pragma unroll
  for (int n = 0; n < 16; ++n) {
    int d = n * 16 + qr;
#pragma unroll
    for (int j = 0; j < 4; ++j) {
      int t = myq0 + kg * 4 + j;
      float val = o[n][j] / lrun[j];
      float g = bf2f(qkv[(size_t)t * 9216 + h * 512 + 256 + d]);
      val *= 1.0f / (1.0f + __expf(-g));
      A2[(size_t)t * 4096 + h * 256 + d] = f2bf(val);
    }
  }
}

// ---------- launch ----------
extern "C" void kernel_launch(void* const* d_in, const int* in_sizes, int n_in,
                              void* d_out, int out_size, void* d_ws, size_t ws_size,
                              hipStream_t stream) {
  const float* hidden = (const float*)d_in[0];
  const int* positions = (const int*)d_in[1];
  const float* w_qkv = (const float*)d_in[2];
  const float* w_o = (const float*)d_in[3];
  const float* q_norm_w = (const float*)d_in[4];
  const float* k_norm_w = (const float*)d_in[5];

  char* ws = (char*)d_ws;
  ushort_t* hb    = (ushort_t*)ws;                          // 16,777,216 B  hidden bf16
  ushort_t* wqkvT = (ushort_t*)(ws + 16777216);             // 37,748,736 B  w_qkv^T bf16 (9216,2048)
  ushort_t* woT   = (ushort_t*)(ws + 54525952);             // 16,777,216 B  w_o^T bf16 (2048,4096)
  ushort_t* qkvb  = (ushort_t*)(ws + 71303168);             // 75,497,472 B  qkv bf16 (4096,9216)
  ushort_t* A2    = (ushort_t*)(ws + 146800640);            // 33,554,432 B  gated attn bf16 (4096,4096)

  hipLaunchKernelGGL(cast_bf16_kernel, dim3(4096), dim3(256), 0, stream,
                     hidden, hb, 1048576);
  hipLaunchKernelGGL(transpose_cast_kernel, dim3(288, 64), dim3(32, 8), 0, stream,
                     w_qkv, wqkvT, 2048, 9216);
  hipLaunchKernelGGL(transpose_cast_kernel, dim3(64, 128), dim3(32, 8), 0, stream,
                     w_o, woT, 4096, 2048);
  hipLaunchKernelGGL((gemm_bt_kernel<1>), dim3(72, 32), dim3(256), 0, stream,
                     hb, wqkvT, (void*)qkvb, 4096, 9216, 2048);
  hipLaunchKernelGGL(normrope_kernel, dim3(18432), dim3(256), 0, stream,
                     qkvb, positions, q_norm_w, k_norm_w);
  hipLaunchKernelGGL(attn_kernel, dim3(64, 16), dim3(256), 0, stream,
                     qkvb, A2);
  hipLaunchKernelGGL((gemm_bt_kernel<0>), dim3(16, 32), dim3(256), 0, stream,
                     A2, woT, d_out, 4096, 2048, 4096);
}

// Round 2
// 812.669 us; speedup vs baseline: 1.3246x; 1.3246x over previous
//
#include <hip/hip_runtime.h>

typedef __attribute__((ext_vector_type(4))) float f32x4;
typedef __attribute__((ext_vector_type(8))) __bf16 bf16x8;
typedef unsigned short ushort_t;
typedef unsigned int uint_t;

// ---------- bf16 helpers (manual, RNE) ----------
__device__ __forceinline__ float bf2f(ushort_t u) {
  union { uint_t i; float f; } v; v.i = ((uint_t)u) << 16; return v.f;
}
__device__ __forceinline__ ushort_t f2bf(float f) {
  union { float f; uint_t i; } v; v.f = f;
  uint_t x = v.i;
  return (ushort_t)((x + 0x7fffu + ((x >> 16) & 1u)) >> 16);
}

// ---------- async global->LDS, 16B ----------
__device__ __forceinline__ void gload_lds16(const void* g, void* l) {
  __builtin_amdgcn_global_load_lds(
      (const __attribute__((address_space(1))) void*)g,
      (__attribute__((address_space(3))) void*)l, 16, 0, 0);
}

// ---------- 1) fp32 -> bf16 cast (8 elems/thread) ----------
__global__ __launch_bounds__(256) void cast_bf16_kernel(
    const float* __restrict__ in, ushort_t* __restrict__ out, int n8) {
  int i = blockIdx.x * 256 + threadIdx.x;
  if (i >= n8) return;
  float4 a = ((const float4*)in)[i * 2];
  float4 b = ((const float4*)in)[i * 2 + 1];
  ushort4 o0 = make_ushort4(f2bf(a.x), f2bf(a.y), f2bf(a.z), f2bf(a.w));
  ushort4 o1 = make_ushort4(f2bf(b.x), f2bf(b.y), f2bf(b.z), f2bf(b.w));
  ((ushort4*)out)[i * 2] = o0;
  ((ushort4*)out)[i * 2 + 1] = o1;
}

// ---------- 2) transpose + cast: in (R,C) fp32 -> out (C,R) bf16 ----------
__global__ __launch_bounds__(256) void transpose_cast_kernel(
    const float* __restrict__ in, ushort_t* __restrict__ out, int R, int C) {
  __shared__ float tile[32][33];
  int tx = threadIdx.x, ty = threadIdx.y;
  int c0 = blockIdx.x * 32, r0 = blockIdx.y * 32;
#pragma unroll
  for (int i = 0; i < 4; ++i)
    tile[ty + i * 8][tx] = in[(size_t)(r0 + ty + i * 8) * C + c0 + tx];
  __syncthreads();
#pragma unroll
  for (int i = 0; i < 4; ++i)
    out[(size_t)(c0 + ty + i * 8) * R + r0 + tx] = f2bf(tile[tx][ty + i * 8]);
}

// ---------- 3) GEMM: C(M,N) = A(M,K)bf16 * BT(N,K)bf16 ----------
// 128x128 tile, BK=32, 4 waves (2x2), each wave 64x64 via 4x4 16x16x32 MFMAs.
template <int OUT_BF16>
__global__ __launch_bounds__(256, 2) void gemm_bt_kernel(
    const ushort_t* __restrict__ A, const ushort_t* __restrict__ BT,
    void* __restrict__ Cout, int M, int N, int K) {
  __shared__ ushort_t As[128 * 32];
  __shared__ ushort_t Bs[128 * 32];
  const int tid = threadIdx.x;
  const int lane = tid & 63;
  const int wid = tid >> 6;
  const int wr = wid >> 1, wc = wid & 1;
  const int qr = lane & 15, kg = lane >> 4;
  const size_t arow = (size_t)blockIdx.y * 128;
  const size_t brow = (size_t)blockIdx.x * 128;

  f32x4 acc[4][4] = {};

  for (int k0 = 0; k0 < K; k0 += 32) {
    __syncthreads();
#pragma unroll
    for (int t = 0; t < 2; ++t) {
      int c = (t * 4 + wid) * 64 + lane;
      int r = c >> 2, kc = (c & 3) * 8;
      gload_lds16(A + (arow + r) * K + k0 + kc, &As[(t * 4 + wid) * 512]);
      gload_lds16(BT + (brow + r) * K + k0 + kc, &Bs[(t * 4 + wid) * 512]);
    }
    __syncthreads();
    bf16x8 af[4], bfr[4];
#pragma unroll
    for (int m = 0; m < 4; ++m)
      af[m] = *(const bf16x8*)&As[(wr * 64 + m * 16 + qr) * 32 + kg * 8];
#pragma unroll
    for (int n = 0; n < 4; ++n)
      bfr[n] = *(const bf16x8*)&Bs[(wc * 64 + n * 16 + qr) * 32 + kg * 8];
#pragma unroll
    for (int m = 0; m < 4; ++m)
#pragma unroll
      for (int n = 0; n < 4; ++n)
        acc[m][n] = __builtin_amdgcn_mfma_f32_16x16x32_bf16(af[m], bfr[n], acc[m][n], 0, 0, 0);
  }

#pragma unroll
  for (int m = 0; m < 4; ++m)
#pragma unroll
    for (int n = 0; n < 4; ++n)
#pragma unroll
      for (int j = 0; j < 4; ++j) {
        size_t row = arow + wr * 64 + m * 16 + kg * 4 + j;
        size_t col = brow + wc * 64 + n * 16 + qr;
        float v = acc[m][n][j];
        if (OUT_BF16) ((ushort_t*)Cout)[row * N + col] = f2bf(v);
        else ((float*)Cout)[row * N + col] = v;
      }
}

// ---------- 4) fused Gemma-RMSNorm + RoPE on q/k rows of qkv, in place ----------
// one wave per (token, head-slot); slots 0..15 = q heads, 16..17 = k heads.
__global__ __launch_bounds__(256) void normrope_kernel(
    ushort_t* __restrict__ qkv, const int* __restrict__ positions,
    const float* __restrict__ qw, const float* __restrict__ kw) {
  const int wv = blockIdx.x * 4 + (threadIdx.x >> 6);
  const int lane = threadIdx.x & 63;
  const int t = wv / 18;
  const int idx = wv % 18;
  size_t base;
  const float* w;
  if (idx < 16) { base = (size_t)t * 9216 + idx * 512; w = qw; }
  else { base = (size_t)t * 9216 + 8192 + (size_t)(idx - 16) * 256; w = kw; }

  ushort4 raw = *(const ushort4*)(qkv + base + lane * 4);
  float x0 = bf2f(raw.x), x1 = bf2f(raw.y), x2 = bf2f(raw.z), x3 = bf2f(raw.w);
  float ss = x0 * x0 + x1 * x1 + x2 * x2 + x3 * x3;
#pragma unroll
  for (int off = 1; off < 64; off <<= 1) ss += __shfl_xor(ss, off);
  float inv = rsqrtf(ss * (1.0f / 256.0f) + 1e-6f);
  const int d0 = lane * 4;
  float xn[4] = { x0 * inv * (1.f + w[d0]), x1 * inv * (1.f + w[d0 + 1]),
                  x2 * inv * (1.f + w[d0 + 2]), x3 * inv * (1.f + w[d0 + 3]) };
  float pn[4];
#pragma unroll
  for (int j = 0; j < 4; ++j) pn[j] = __shfl_xor(xn[j], 8);
  if (lane < 16) {
    const float pos = (float)positions[t];
#pragma unroll
    for (int j = 0; j < 4; ++j) {
      int d = d0 + j;
      int i = d & 31;
      float invf = __expf(-(float)i * 0.28782313662425574f);  // 10000^(-i/32)
      float fr = pos * invf;
      float s, c;
      sincosf(fr, &s, &c);
      xn[j] = (d < 32) ? (xn[j] * c - pn[j] * s) : (xn[j] * c + pn[j] * s);
    }
  }
  ushort4 o = make_ushort4(f2bf(xn[0]), f2bf(xn[1]), f2bf(xn[2]), f2bf(xn[3]));
  *(ushort4*)(qkv + base + lane * 4) = o;
}

// ---------- 5) causal flash attention + sigmoid gate ----------
// Flat grid of 1024 blocks; per-block (qt,h) decoded with a work-balance
// swizzle: residency slot g = id&255 gets k=id>>8 in {0..3} with
// qt in {48+x, 47-x, 16+x, 15-x} (x = g>>4) -> constant work per slot,
// longest blocks first; kvh = id&1 so each XCD's L2 caches one kv head.
__global__ __launch_bounds__(256, 2) void attn_kernel(
    const ushort_t* __restrict__ qkv, ushort_t* __restrict__ A2) {
  const int id = blockIdx.x;
  const int g = id & 255, kk = id >> 8;
  const int h = ((g & 1) << 3) | ((g >> 1) & 7);
  const int x = g >> 4;
  const int qt = (3 - kk) * 16 + ((kk & 1) ? (15 - x) : x);
  const int kvh = h >> 3;
  const int tid = threadIdx.x;
  const int lane = tid & 63;
  const int wid = tid >> 6;
  const int qr = lane & 15, kg = lane >> 4;

  __shared__ ushort_t Ks[32 * 256];      // [kv][d], 16B-chunk XOR swizzled
  __shared__ ushort_t Vt[256 * 32];      // [d][kv], chunk XOR swizzled
  __shared__ ushort_t Ps[4][16 * 40];    // per-wave P tile [q16][kv32], stride 40

  const int q0 = qt * 64;
  const int myq0 = q0 + wid * 16;

  bf16x8 qf[8];
#pragma unroll
  for (int kd = 0; kd < 8; ++kd)
    qf[kd] = *(const bf16x8*)(qkv + (size_t)(myq0 + qr) * 9216 + h * 512 + kd * 32 + kg * 8);

  f32x4 o[16] = {};
  float mrun[4], lrun[4];
#pragma unroll
  for (int j = 0; j < 4; ++j) { mrun[j] = -1e30f; lrun[j] = 0.f; }

  const int ntiles = qt * 2 + 2;
  for (int kt = 0; kt < ntiles; ++kt) {
    const int kv0 = kt * 32;
    __syncthreads();
    // stage K: 1024 chunks of 16B; LDS linear, global source pre-swizzled
#pragma unroll
    for (int t = 0; t < 4; ++t) {
      int c = (t * 4 + wid) * 64 + lane;
      int r = c >> 5, dc = c & 31;
      int dcs = dc ^ (r & 7);
      gload_lds16(qkv + (size_t)(kv0 + r) * 9216 + 8192 + kvh * 256 + dcs * 8,
                  &Ks[(t * 4 + wid) * 512]);
    }
    // stage V^T via register transpose (packed b32 writes), swizzled
#pragma unroll
    for (int t = 0; t < 2; ++t) {
      int p = tid + 256 * t;
      int kvp = (p & 15) * 2, dc = p >> 4;
      const ushort_t* g0 = qkv + (size_t)(kv0 + kvp) * 9216 + 8704 + kvh * 256 + dc * 8;
      ushort4 a0 = *(const ushort4*)g0;
      ushort4 a1 = *(const ushort4*)(g0 + 4);
      ushort4 b0 = *(const ushort4*)(g0 + 9216);
      ushort4 b1 = *(const ushort4*)(g0 + 9216 + 4);
      uint_t vals[8];
      vals[0] = a0.x | ((uint_t)b0.x << 16); vals[1] = a0.y | ((uint_t)b0.y << 16);
      vals[2] = a0.z | ((uint_t)b0.z << 16); vals[3] = a0.w | ((uint_t)b0.w << 16);
      vals[4] = a1.x | ((uint_t)b1.x << 16); vals[5] = a1.y | ((uint_t)b1.y << 16);
      vals[6] = a1.z | ((uint_t)b1.z << 16); vals[7] = a1.w | ((uint_t)b1.w << 16);
#pragma unroll
      for (int j = 0; j < 8; ++j) {
        int d = dc * 8 + j;
        int boff = d * 64 + (((kvp >> 3) ^ (d & 3)) * 16) + ((kvp * 2) & 15);
        *(uint_t*)((char*)Vt + boff) = vals[j];
      }
    }
    __syncthreads();

    const bool active = (kv0 <= myq0 + 15);  // wave-uniform causal skip
    if (active) {
      f32x4 s0 = {0.f, 0.f, 0.f, 0.f}, s1 = {0.f, 0.f, 0.f, 0.f};
#pragma unroll
      for (int kd = 0; kd < 8; ++kd) {
        int kvr0 = qr;
        int off0 = kvr0 * 512 + ((kd * 64 + kg * 16) ^ ((kvr0 & 7) << 4));
        bf16x8 kf0 = *(const bf16x8*)((const char*)Ks + off0);
        s0 = __builtin_amdgcn_mfma_f32_16x16x32_bf16(qf[kd], kf0, s0, 0, 0, 0);
        int kvr1 = 16 + qr;
        int off1 = kvr1 * 512 + ((kd * 64 + kg * 16) ^ ((kvr1 & 7) << 4));
        bf16x8 kf1 = *(const bf16x8*)((const char*)Ks + off1);
        s1 = __builtin_amdgcn_mfma_f32_16x16x32_bf16(qf[kd], kf1, s1, 0, 0, 0);
      }
      // online softmax (per lane: 4 q-rows = kg*4+j; kv cols = n*16+qr)
      // with defer-max (T13, THR=8): skip O-rescale when max growth small.
#pragma unroll
      for (int j = 0; j < 4; ++j) {
        int qg = myq0 + kg * 4 + j;
        float v0 = s0[j] * 0.0625f, v1 = s1[j] * 0.0625f;
        if (kv0 + qr > qg) v0 = -1e30f;
        if (kv0 + 16 + qr > qg) v1 = -1e30f;
        float tm = fmaxf(v0, v1);
#pragma unroll
        for (int off = 1; off < 16; off <<= 1) tm = fmaxf(tm, __shfl_xor(tm, off));
        float mref;
        if (__all(tm - mrun[j] <= 8.0f)) {
          mref = mrun[j];                     // defer: no rescale this tile
        } else {
          float mnew = fmaxf(mrun[j], tm);
          float corr = __expf(mrun[j] - mnew);
          lrun[j] *= corr;
#pragma unroll
          for (int n = 0; n < 16; ++n) o[n][j] *= corr;
          mrun[j] = mnew;
          mref = mnew;
        }
        float p0 = __expf(v0 - mref), p1 = __expf(v1 - mref);
        float ps = p0 + p1;
#pragma unroll
        for (int off = 1; off < 16; off <<= 1) ps += __shfl_xor(ps, off);
        lrun[j] += ps;
        Ps[wid][(kg * 4 + j) * 40 + qr] = f2bf(p0);
        Ps[wid][(kg * 4 + j) * 40 + 16 + qr] = f2bf(p1);
      }
      asm volatile("" ::: "memory");  // order P writes before P read (same wave)
      bf16x8 pf = *(const bf16x8*)&Ps[wid][qr * 40 + kg * 8];
#pragma unroll
      for (int n = 0; n < 16; ++n) {
        int dcol = n * 16 + qr;
        int boff = dcol * 64 + ((kg ^ (dcol & 3)) * 16);
        bf16x8 vf = *(const bf16x8*)((const char*)Vt + boff);
        o[n] = __builtin_amdgcn_mfma_f32_16x16x32_bf16(pf, vf, o[n], 0, 0, 0);
      }
    }
  }

  // epilogue: 1/l, sigmoid gate, bf16 store
#pragma unroll
  for (int n = 0; n < 16; ++n) {
    int d = n * 16 + qr;
#pragma unroll
    for (int j = 0; j < 4; ++j) {
      int t = myq0 + kg * 4 + j;
      float val = o[n][j] / lrun[j];
      float g2 = bf2f(qkv[(size_t)t * 9216 + h * 512 + 256 + d]);
      val *= 1.0f / (1.0f + __expf(-g2));
      A2[(size_t)t * 4096 + h * 256 + d] = f2bf(val);
    }
  }
}

// ---------- launch ----------
extern "C" void kernel_launch(void* const* d_in, const int* in_sizes, int n_in,
                              void* d_out, int out_size, void* d_ws, size_t ws_size,
                              hipStream_t stream) {
  const float* hidden = (const float*)d_in[0];
  const int* positions = (const int*)d_in[1];
  const float* w_qkv = (const float*)d_in[2];
  const float* w_o = (const float*)d_in[3];
  const float* q_norm_w = (const float*)d_in[4];
  const float* k_norm_w = (const float*)d_in[5];

  char* ws = (char*)d_ws;
  ushort_t* hb    = (ushort_t*)ws;                          // 16,777,216 B  hidden bf16
  ushort_t* wqkvT = (ushort_t*)(ws + 16777216);             // 37,748,736 B  w_qkv^T bf16 (9216,2048)
  ushort_t* woT   = (ushort_t*)(ws + 54525952);             // 16,777,216 B  w_o^T bf16 (2048,4096)
  ushort_t* qkvb  = (ushort_t*)(ws + 71303168);             // 75,497,472 B  qkv bf16 (4096,9216)
  ushort_t* A2    = (ushort_t*)(ws + 146800640);            // 33,554,432 B  gated attn bf16 (4096,4096)

  hipLaunchKernelGGL(cast_bf16_kernel, dim3(4096), dim3(256), 0, stream,
                     hidden, hb, 1048576);
  hipLaunchKernelGGL(transpose_cast_kernel, dim3(288, 64), dim3(32, 8), 0, stream,
                     w_qkv, wqkvT, 2048, 9216);
  hipLaunchKernelGGL(transpose_cast_kernel, dim3(64, 128), dim3(32, 8), 0, stream,
                     w_o, woT, 4096, 2048);
  hipLaunchKernelGGL((gemm_bt_kernel<1>), dim3(72, 32), dim3(256), 0, stream,
                     hb, wqkvT, (void*)qkvb, 4096, 9216, 2048);
  hipLaunchKernelGGL(normrope_kernel, dim3(18432), dim3(256), 0, stream,
                     qkvb, positions, q_norm_w, k_norm_w);
  hipLaunchKernelGGL(attn_kernel, dim3(1024), dim3(256), 0, stream,
                     qkvb, A2);
  hipLaunchKernelGGL((gemm_bt_kernel<0>), dim3(16, 32), dim3(256), 0, stream,
                     A2, woT, d_out, 4096, 2048, 4096);
}

// Round 3
// 728.652 us; speedup vs baseline: 1.4774x; 1.1153x over previous
//
#include <hip/hip_runtime.h>

typedef __attribute__((ext_vector_type(4))) float f32x4;
typedef __attribute__((ext_vector_type(8))) __bf16 bf16x8;
typedef unsigned short ushort_t;
typedef unsigned int uint_t;
typedef __attribute__((ext_vector_type(4))) uint_t u32x4;

// ---------- bf16 helpers (manual, RNE) ----------
__device__ __forceinline__ float bf2f(ushort_t u) {
  union { uint_t i; float f; } v; v.i = ((uint_t)u) << 16; return v.f;
}
__device__ __forceinline__ ushort_t f2bf(float f) {
  union { float f; uint_t i; } v; v.f = f;
  uint_t x = v.i;
  return (ushort_t)((x + 0x7fffu + ((x >> 16) & 1u)) >> 16);
}

// ---------- async global->LDS, 16B ----------
__device__ __forceinline__ void gload_lds16(const void* g, void* l) {
  __builtin_amdgcn_global_load_lds(
      (const __attribute__((address_space(1))) void*)g,
      (__attribute__((address_space(3))) void*)l, 16, 0, 0);
}

// ---------- 1) fp32 -> bf16 cast (8 elems/thread) ----------
__global__ __launch_bounds__(256) void cast_bf16_kernel(
    const float* __restrict__ in, ushort_t* __restrict__ out, int n8) {
  int i = blockIdx.x * 256 + threadIdx.x;
  if (i >= n8) return;
  float4 a = ((const float4*)in)[i * 2];
  float4 b = ((const float4*)in)[i * 2 + 1];
  ushort4 o0 = make_ushort4(f2bf(a.x), f2bf(a.y), f2bf(a.z), f2bf(a.w));
  ushort4 o1 = make_ushort4(f2bf(b.x), f2bf(b.y), f2bf(b.z), f2bf(b.w));
  ((ushort4*)out)[i * 2] = o0;
  ((ushort4*)out)[i * 2 + 1] = o1;
}

// ---------- 2) transpose + cast: in (R,C) fp32 -> out (C,R) bf16 ----------
__global__ __launch_bounds__(256) void transpose_cast_kernel(
    const float* __restrict__ in, ushort_t* __restrict__ out, int R, int C) {
  __shared__ float tile[32][33];
  int tx = threadIdx.x, ty = threadIdx.y;
  int c0 = blockIdx.x * 32, r0 = blockIdx.y * 32;
#pragma unroll
  for (int i = 0; i < 4; ++i)
    tile[ty + i * 8][tx] = in[(size_t)(r0 + ty + i * 8) * C + c0 + tx];
  __syncthreads();
#pragma unroll
  for (int i = 0; i < 4; ++i)
    out[(size_t)(c0 + ty + i * 8) * R + r0 + tx] = f2bf(tile[tx][ty + i * 8]);
}

// ---------- 3) GEMM: C(M,N) = A(M,K)bf16 * BT(N,K)bf16 ----------
// 128x128 tile, BK=32, 4 waves (2x2), each wave 64x64 via 4x4 16x16x32 MFMAs.
template <int OUT_BF16>
__global__ __launch_bounds__(256, 2) void gemm_bt_kernel(
    const ushort_t* __restrict__ A, const ushort_t* __restrict__ BT,
    void* __restrict__ Cout, int M, int N, int K) {
  __shared__ ushort_t As[128 * 32];
  __shared__ ushort_t Bs[128 * 32];
  const int tid = threadIdx.x;
  const int lane = tid & 63;
  const int wid = tid >> 6;
  const int wr = wid >> 1, wc = wid & 1;
  const int qr = lane & 15, kg = lane >> 4;
  const size_t arow = (size_t)blockIdx.y * 128;
  const size_t brow = (size_t)blockIdx.x * 128;

  f32x4 acc[4][4] = {};

  for (int k0 = 0; k0 < K; k0 += 32) {
    __syncthreads();
#pragma unroll
    for (int t = 0; t < 2; ++t) {
      int c = (t * 4 + wid) * 64 + lane;
      int r = c >> 2, kc = (c & 3) * 8;
      gload_lds16(A + (arow + r) * K + k0 + kc, &As[(t * 4 + wid) * 512]);
      gload_lds16(BT + (brow + r) * K + k0 + kc, &Bs[(t * 4 + wid) * 512]);
    }
    __syncthreads();
    bf16x8 af[4], bfr[4];
#pragma unroll
    for (int m = 0; m < 4; ++m)
      af[m] = *(const bf16x8*)&As[(wr * 64 + m * 16 + qr) * 32 + kg * 8];
#pragma unroll
    for (int n = 0; n < 4; ++n)
      bfr[n] = *(const bf16x8*)&Bs[(wc * 64 + n * 16 + qr) * 32 + kg * 8];
#pragma unroll
    for (int m = 0; m < 4; ++m)
#pragma unroll
      for (int n = 0; n < 4; ++n)
        acc[m][n] = __builtin_amdgcn_mfma_f32_16x16x32_bf16(af[m], bfr[n], acc[m][n], 0, 0, 0);
  }

#pragma unroll
  for (int m = 0; m < 4; ++m)
#pragma unroll
    for (int n = 0; n < 4; ++n)
#pragma unroll
      for (int j = 0; j < 4; ++j) {
        size_t row = arow + wr * 64 + m * 16 + kg * 4 + j;
        size_t col = brow + wc * 64 + n * 16 + qr;
        float v = acc[m][n][j];
        if (OUT_BF16) ((ushort_t*)Cout)[row * N + col] = f2bf(v);
        else ((float*)Cout)[row * N + col] = v;
      }
}

// ---------- 4) fused Gemma-RMSNorm + RoPE on q/k rows of qkv, in place ----------
__global__ __launch_bounds__(256) void normrope_kernel(
    ushort_t* __restrict__ qkv, const int* __restrict__ positions,
    const float* __restrict__ qw, const float* __restrict__ kw) {
  const int wv = blockIdx.x * 4 + (threadIdx.x >> 6);
  const int lane = threadIdx.x & 63;
  const int t = wv / 18;
  const int idx = wv % 18;
  size_t base;
  const float* w;
  if (idx < 16) { base = (size_t)t * 9216 + idx * 512; w = qw; }
  else { base = (size_t)t * 9216 + 8192 + (size_t)(idx - 16) * 256; w = kw; }

  ushort4 raw = *(const ushort4*)(qkv + base + lane * 4);
  float x0 = bf2f(raw.x), x1 = bf2f(raw.y), x2 = bf2f(raw.z), x3 = bf2f(raw.w);
  float ss = x0 * x0 + x1 * x1 + x2 * x2 + x3 * x3;
#pragma unroll
  for (int off = 1; off < 64; off <<= 1) ss += __shfl_xor(ss, off);
  float inv = rsqrtf(ss * (1.0f / 256.0f) + 1e-6f);
  const int d0 = lane * 4;
  float xn[4] = { x0 * inv * (1.f + w[d0]), x1 * inv * (1.f + w[d0 + 1]),
                  x2 * inv * (1.f + w[d0 + 2]), x3 * inv * (1.f + w[d0 + 3]) };
  float pn[4];
#pragma unroll
  for (int j = 0; j < 4; ++j) pn[j] = __shfl_xor(xn[j], 8);
  if (lane < 16) {
    const float pos = (float)positions[t];
#pragma unroll
    for (int j = 0; j < 4; ++j) {
      int d = d0 + j;
      int i = d & 31;
      float invf = __expf(-(float)i * 0.28782313662425574f);  // 10000^(-i/32)
      float fr = pos * invf;
      float s, c;
      sincosf(fr, &s, &c);
      xn[j] = (d < 32) ? (xn[j] * c - pn[j] * s) : (xn[j] * c + pn[j] * s);
    }
  }
  ushort4 o = make_ushort4(f2bf(xn[0]), f2bf(xn[1]), f2bf(xn[2]), f2bf(xn[3]));
  *(ushort4*)(qkv + base + lane * 4) = o;
}

// ---------- 5) causal flash attention + sigmoid gate ----------
// LPT dispatch: descending qt; kvh = id&1 pins one KV head per XCD.
// Pipelined: double-buffered K (gload_lds) + V (global->reg->LDS, T14 split),
// ONE barrier per KV tile; stage issue of t+1 overlaps compute of t (T3).
// KV slot order interleaved (slot 2r <-> kv r, 2r+1 <-> kv r+16) so P writes
// are packed b32; V^T rows XOR-swizzled (d ^ ((d>>3)&1)) for 2-way-free banks.
__global__ __launch_bounds__(256, 2) void attn_kernel(
    const ushort_t* __restrict__ qkv, ushort_t* __restrict__ A2) {
  const int id = blockIdx.x;
  const int kvh = id & 1;
  const int j2 = id >> 1;
  const int qt = 63 - (j2 >> 3);
  const int h = kvh * 8 + (j2 & 7);
  const int tid = threadIdx.x;
  const int lane = tid & 63;
  const int wid = tid >> 6;
  const int qr = lane & 15, kg = lane >> 4;

  __shared__ __align__(16) ushort_t Ks[2][32 * 256];  // [kv][d], 16B-chunk XOR swz
  __shared__ __align__(16) ushort_t Vt[2][256 * 32];  // [d'][slot], row+chunk swz
  __shared__ __align__(16) ushort_t Ps[4][16 * 40];   // [q16][slot32], pitch 80B

  const int q0 = qt * 64;
  const int myq0 = q0 + wid * 16;

  bf16x8 qf[8];
#pragma unroll
  for (int kd = 0; kd < 8; ++kd)
    qf[kd] = *(const bf16x8*)(qkv + (size_t)(myq0 + qr) * 9216 + h * 512 + kd * 32 + kg * 8);

  f32x4 o[16] = {};
  float mrun[4], lrun[4];
#pragma unroll
  for (int j = 0; j < 4; ++j) { mrun[j] = -1e30f; lrun[j] = 0.f; }

  const int nt = qt * 2 + 2;

  // V-reg staging state (lives across compute; static-indexed)
  u32x4 vlo0, vhi0, vlo1, vhi1;
  const int vr = tid & 15;            // kv pair index (vr, vr+16)
  const int vd0 = (tid >> 4) * 8;     // d base, thread-iter 0 (d 0..127)
  const int vd1 = vd0 + 128;          // thread-iter 1 (d 128..255)

  // prologue: issue K(0) + V(0)
#pragma unroll
  for (int t = 0; t < 4; ++t) {
    int c = (t * 4 + wid) * 64 + lane;
    int r = c >> 5, dc = c & 31;
    int dcs = dc ^ (r & 7);
    gload_lds16(qkv + (size_t)r * 9216 + 8192 + kvh * 256 + dcs * 8,
                &Ks[0][(t * 4 + wid) * 512]);
  }
  {
    const ushort_t* g0 = qkv + (size_t)vr * 9216 + 8704 + kvh * 256;
    vlo0 = *(const u32x4*)(g0 + vd0);
    vhi0 = *(const u32x4*)(g0 + 16 * 9216 + vd0);
    vlo1 = *(const u32x4*)(g0 + vd1);
    vhi1 = *(const u32x4*)(g0 + 16 * 9216 + vd1);
  }

  int buf = 0;
  for (int kt = 0; kt < nt; ++kt) {
    const int kv0 = kt * 32;

    // ---- write V^T(t) from regs into Vt[buf] (vmcnt waits auto-inserted) ----
    {
      char* vbase = (char*)&Vt[buf][0];
#pragma unroll
      for (int half = 0; half < 2; ++half) {
        u32x4 lo = half ? vlo1 : vlo0;
        u32x4 hi = half ? vhi1 : vhi0;
        int dbase = half ? vd1 : vd0;
#pragma unroll
        for (int w = 0; w < 4; ++w) {
          uint_t v0 = (lo[w] & 0xffffu) | (hi[w] << 16);
          uint_t v1 = (lo[w] >> 16) | (hi[w] & 0xffff0000u);
          int d0v = dbase + 2 * w, d1v = d0v + 1;
          int rsw = ((vr >> 2) * 16) + (vr & 3) * 4;
          *(uint_t*)(vbase + (d0v ^ ((d0v >> 3) & 1)) * 64 +
                     (rsw ^ ((d0v & 3) * 16))) = v0;
          *(uint_t*)(vbase + (d1v ^ ((d1v >> 3) & 1)) * 64 +
                     (rsw ^ ((d1v & 3) * 16))) = v1;
        }
      }
    }
    __syncthreads();  // drains vmcnt/lgkmcnt: K(t) in LDS, V^T(t) visible

    // ---- issue stage of tile t+1 into the other buffer ----
    if (kt + 1 < nt) {
      const int kv0n = kv0 + 32;
#pragma unroll
      for (int t = 0; t < 4; ++t) {
        int c = (t * 4 + wid) * 64 + lane;
        int r = c >> 5, dc = c & 31;
        int dcs = dc ^ (r & 7);
        gload_lds16(qkv + (size_t)(kv0n + r) * 9216 + 8192 + kvh * 256 + dcs * 8,
                    &Ks[buf ^ 1][(t * 4 + wid) * 512]);
      }
      const ushort_t* g0 = qkv + (size_t)(kv0n + vr) * 9216 + 8704 + kvh * 256;
      vlo0 = *(const u32x4*)(g0 + vd0);
      vhi0 = *(const u32x4*)(g0 + 16 * 9216 + vd0);
      vlo1 = *(const u32x4*)(g0 + vd1);
      vhi1 = *(const u32x4*)(g0 + 16 * 9216 + vd1);
    }
    __builtin_amdgcn_sched_barrier(0);  // keep stage issues above compute

    // ---- compute tile t ----
    const bool active = (kv0 <= myq0 + 15);  // wave-uniform causal skip
    if (active) {
      const ushort_t* ksb = &Ks[buf][0];
      f32x4 s0 = {0.f, 0.f, 0.f, 0.f}, s1 = {0.f, 0.f, 0.f, 0.f};
#pragma unroll
      for (int kd = 0; kd < 8; ++kd) {
        int off0 = qr * 512 + ((kd * 64 + kg * 16) ^ ((qr & 7) << 4));
        bf16x8 kf0 = *(const bf16x8*)((const char*)ksb + off0);
        s0 = __builtin_amdgcn_mfma_f32_16x16x32_bf16(qf[kd], kf0, s0, 0, 0, 0);
        int kvr1 = 16 + qr;
        int off1 = kvr1 * 512 + ((kd * 64 + kg * 16) ^ ((kvr1 & 7) << 4));
        bf16x8 kf1 = *(const bf16x8*)((const char*)ksb + off1);
        s1 = __builtin_amdgcn_mfma_f32_16x16x32_bf16(qf[kd], kf1, s1, 0, 0, 0);
      }
      // online softmax; defer-max (T13, THR=8)
#pragma unroll
      for (int j = 0; j < 4; ++j) {
        int qg = myq0 + kg * 4 + j;
        float v0 = s0[j] * 0.0625f, v1 = s1[j] * 0.0625f;
        if (kv0 + qr > qg) v0 = -1e30f;
        if (kv0 + 16 + qr > qg) v1 = -1e30f;
        float tm = fmaxf(v0, v1);
#pragma unroll
        for (int off = 1; off < 16; off <<= 1) tm = fmaxf(tm, __shfl_xor(tm, off));
        float mref;
        if (__all(tm - mrun[j] <= 8.0f)) {
          mref = mrun[j];
        } else {
          float mnew = fmaxf(mrun[j], tm);
          float corr = __expf(mrun[j] - mnew);
          lrun[j] *= corr;
#pragma unroll
          for (int n = 0; n < 16; ++n) o[n][j] *= corr;
          mrun[j] = mnew;
          mref = mnew;
        }
        float p0 = __expf(v0 - mref), p1 = __expf(v1 - mref);
        float ps = p0 + p1;
#pragma unroll
        for (int off = 1; off < 16; off <<= 1) ps += __shfl_xor(ps, off);
        lrun[j] += ps;
        // packed b32: slot 2qr = p0 (kv=qr), slot 2qr+1 = p1 (kv=16+qr)
        *(uint_t*)((char*)&Ps[wid][0] + (kg * 4 + j) * 80 + qr * 4) =
            (uint_t)f2bf(p0) | ((uint_t)f2bf(p1) << 16);
      }
      asm volatile("" ::: "memory");  // order P writes before P read (same wave)
      bf16x8 pf = *(const bf16x8*)&Ps[wid][qr * 40 + kg * 8];
      const char* vtb = (const char*)&Vt[buf][0];
#pragma unroll
      for (int n = 0; n < 16; ++n) {
        int dcol = n * 16 + qr;
        int dsw = dcol ^ ((dcol >> 3) & 1);
        bf16x8 vf = *(const bf16x8*)(vtb + dsw * 64 + ((kg ^ (dcol & 3)) * 16));
        o[n] = __builtin_amdgcn_mfma_f32_16x16x32_bf16(pf, vf, o[n], 0, 0, 0);
      }
    }
    buf ^= 1;
  }

  // epilogue: 1/l, sigmoid gate, bf16 store
#pragma unroll
  for (int n = 0; n < 16; ++n) {
    int d = n * 16 + qr;
#pragma unroll
    for (int j = 0; j < 4; ++j) {
      int t = myq0 + kg * 4 + j;
      float val = o[n][j] / lrun[j];
      float g2 = bf2f(qkv[(size_t)t * 9216 + h * 512 + 256 + d]);
      val *= 1.0f / (1.0f + __expf(-g2));
      A2[(size_t)t * 4096 + h * 256 + d] = f2bf(val);
    }
  }
}

// ---------- launch ----------
extern "C" void kernel_launch(void* const* d_in, const int* in_sizes, int n_in,
                              void* d_out, int out_size, void* d_ws, size_t ws_size,
                              hipStream_t stream) {
  const float* hidden = (const float*)d_in[0];
  const int* positions = (const int*)d_in[1];
  const float* w_qkv = (const float*)d_in[2];
  const float* w_o = (const float*)d_in[3];
  const float* q_norm_w = (const float*)d_in[4];
  const float* k_norm_w = (const float*)d_in[5];

  char* ws = (char*)d_ws;
  ushort_t* hb    = (ushort_t*)ws;                          // 16,777,216 B  hidden bf16
  ushort_t* wqkvT = (ushort_t*)(ws + 16777216);             // 37,748,736 B  w_qkv^T bf16 (9216,2048)
  ushort_t* woT   = (ushort_t*)(ws + 54525952);             // 16,777,216 B  w_o^T bf16 (2048,4096)
  ushort_t* qkvb  = (ushort_t*)(ws + 71303168);             // 75,497,472 B  qkv bf16 (4096,9216)
  ushort_t* A2    = (ushort_t*)(ws + 146800640);            // 33,554,432 B  gated attn bf16 (4096,4096)

  hipLaunchKernelGGL(cast_bf16_kernel, dim3(4096), dim3(256), 0, stream,
                     hidden, hb, 1048576);
  hipLaunchKernelGGL(transpose_cast_kernel, dim3(288, 64), dim3(32, 8), 0, stream,
                     w_qkv, wqkvT, 2048, 9216);
  hipLaunchKernelGGL(transpose_cast_kernel, dim3(64, 128), dim3(32, 8), 0, stream,
                     w_o, woT, 4096, 2048);
  hipLaunchKernelGGL((gemm_bt_kernel<1>), dim3(72, 32), dim3(256), 0, stream,
                     hb, wqkvT, (void*)qkvb, 4096, 9216, 2048);
  hipLaunchKernelGGL(normrope_kernel, dim3(18432), dim3(256), 0, stream,
                     qkvb, positions, q_norm_w, k_norm_w);
  hipLaunchKernelGGL(attn_kernel, dim3(1024), dim3(256), 0, stream,
                     qkvb, A2);
  hipLaunchKernelGGL((gemm_bt_kernel<0>), dim3(16, 32), dim3(256), 0, stream,
                     A2, woT, d_out, 4096, 2048, 4096);
}